// Round 1
// 1350.745 us; speedup vs baseline: 1.8905x; 1.8905x over previous
//
#include <hip/hip_runtime.h>
#include <hip/hip_bf16.h>

#define B_ 2
#define T_ 1024
#define D_ 6144
#define NQ_ 48
#define NKV_ 8
#define HD_ 128
#define GQ_ 6
#define MULT_ 0.08838834764831845f
#define MAXATTN_ 30.0f

typedef __bf16 bf8_t __attribute__((ext_vector_type(8)));
typedef short short8 __attribute__((ext_vector_type(8)));
typedef float f4 __attribute__((ext_vector_type(4)));

__device__ inline float b2f(unsigned short u) {
  return __uint_as_float(((unsigned int)u) << 16);
}
__device__ inline unsigned short f2b(float f) {
  unsigned int u = __float_as_uint(f);
  u += 0x7FFFu + ((u >> 16) & 1u);
  return (unsigned short)(u >> 16);
}
__device__ inline bf8_t ld_frag(const unsigned short* p) {
  return __builtin_bit_cast(bf8_t, *reinterpret_cast<const short8*>(p));
}
__device__ inline f4 mfma16x16(bf8_t a, bf8_t b, f4 c) {
  return __builtin_amdgcn_mfma_f32_16x16x32_bf16(a, b, c, 0, 0, 0);
}
// Async global->LDS, 16B per lane. LDS dest is wave-uniform base; HW writes
// base + lane*16 (m104/m108). Global src per-lane.
__device__ __forceinline__ void gld_lds16(const void* g, void* l) {
  __builtin_amdgcn_global_load_lds(
      (__attribute__((address_space(1))) void*)g,
      (__attribute__((address_space(3))) void*)l, 16, 0, 0);
}

// fp32 -> bf16 flat convert, 8 elems/thread, exact-multiple grids only.
__global__ __launch_bounds__(256) void conv_bf16_k(
    const float* __restrict__ x, unsigned short* __restrict__ y)
{
  size_t i = (size_t)blockIdx.x * 256 + threadIdx.x;
  const f4* xv = (const f4*)x;
  f4 a = xv[2 * i], b = xv[2 * i + 1];
  short8 o;
  #pragma unroll
  for (int j = 0; j < 4; ++j) {
    o[j] = (short)f2b(a[j]);
    o[4 + j] = (short)f2b(b[j]);
  }
  *((short8*)y + i) = o;
}

// W fp32 [K][N] -> Wt bf16 [N][K]. blockDim (32,8); tile: 64 k x 32 n.
__global__ __launch_bounds__(256) void transpose_w_k(
    const float* __restrict__ W, unsigned short* __restrict__ Wt, int K, int N)
{
  __shared__ float t[64][33];
  const int nb = blockIdx.x * 32;
  const int kb = blockIdx.y * 64;
  const int tx = threadIdx.x;  // 0..31
  const int ty = threadIdx.y;  // 0..7
  #pragma unroll
  for (int j = ty; j < 64; j += 8)
    t[j][tx] = W[(size_t)(kb + j) * N + nb + tx];  // coalesced 128B rows
  __syncthreads();
  #pragma unroll
  for (int j = ty; j < 32; j += 8) {
    unsigned int pk = (unsigned int)f2b(t[2 * tx][j]) |
                      ((unsigned int)f2b(t[2 * tx + 1][j]) << 16);
    // packed 4B stores: 32 lanes -> 128B coalesced lines along k
    *reinterpret_cast<unsigned int*>(&Wt[(size_t)(nb + j) * K + kb + 2 * tx]) = pk;
  }
}

// ---------------------------------------------------------------------------
// m97-structure GEMM: C[M,N] = A[M,K] @ Bt[N,K]^T + bias.
// A, Bt bf16 k-contiguous. 128 x BN tile, 4 waves (2x2), K-step 32.
// Both operands staged via global_load_lds width=16 (linear LDS layout).
// Per wave per K-step: 4+FB ds_read_b128, 4*FB MFMA 16x16x32.
// ---------------------------------------------------------------------------
template <int OUT_F32, int BN>
__device__ __forceinline__ void gemm_bt_body(
    const unsigned short* __restrict__ A, const unsigned short* __restrict__ Bt,
    const float* __restrict__ bias, void* __restrict__ Cp,
    int N, int K, int m0, int n0)
{
  constexpr int WN = BN / 2;   // cols per wave
  constexpr int FB = BN / 32;  // b-frags per wave
  constexpr int RB = BN / 64;  // B staging rounds
  __shared__ unsigned short As[128 * 32];
  __shared__ unsigned short Bs[BN * 32];
  const int tid = threadIdx.x;
  const int wave = tid >> 6;
  const int lane = tid & 63;
  const int quad = lane >> 4;
  const int l16 = lane & 15;
  const int wr = wave >> 1;  // wave row 0..1 (64 rows each)
  const int wc = wave & 1;   // wave col 0..1 (WN cols each)
  // staging: chunk c = round*256 + tid covers LDS shorts [c*8, c*8+8)
  // -> row = c>>2 (stride 32 shorts), kcol = (c&3)*8
  const int srow = tid >> 2;
  const int skc = (tid & 3) * 8;

  f4 acc[4][FB];
  #pragma unroll
  for (int i = 0; i < 4; ++i)
    #pragma unroll
    for (int j = 0; j < FB; ++j) acc[i][j] = f4{0.f, 0.f, 0.f, 0.f};

  for (int k0 = 0; k0 < K; k0 += 32) {
    #pragma unroll
    for (int r = 0; r < 2; ++r)
      gld_lds16(A + (size_t)(m0 + r * 64 + srow) * K + k0 + skc,
                &As[(r * 256 + wave * 64) * 8]);
    #pragma unroll
    for (int r = 0; r < RB; ++r)
      gld_lds16(Bt + (size_t)(n0 + r * 64 + srow) * K + k0 + skc,
                &Bs[(r * 256 + wave * 64) * 8]);
    __syncthreads();  // compiler emits vmcnt(0) drain before s_barrier
    bf8_t af[4], bfr[FB];
    #pragma unroll
    for (int i = 0; i < 4; ++i)
      af[i] = ld_frag(&As[(wr * 64 + i * 16 + l16) * 32 + quad * 8]);
    #pragma unroll
    for (int j = 0; j < FB; ++j)
      bfr[j] = ld_frag(&Bs[(wc * WN + j * 16 + l16) * 32 + quad * 8]);
    #pragma unroll
    for (int i = 0; i < 4; ++i)
      #pragma unroll
      for (int j = 0; j < FB; ++j)
        acc[i][j] = mfma16x16(af[i], bfr[j], acc[i][j]);
    __syncthreads();
  }

  #pragma unroll
  for (int j = 0; j < FB; ++j) {
    const int gn = n0 + wc * WN + j * 16 + l16;
    const float bv = bias ? bias[gn] : 0.f;
    #pragma unroll
    for (int i = 0; i < 4; ++i) {
      #pragma unroll
      for (int r = 0; r < 4; ++r) {
        const int gm = m0 + wr * 64 + i * 16 + quad * 4 + r;
        const float v = acc[i][j][r] + bv;
        if constexpr (OUT_F32)
          ((float*)Cp)[(size_t)gm * N + gn] = v;
        else
          ((unsigned short*)Cp)[(size_t)gm * N + gn] = f2b(v);
      }
    }
  }
}

template <int OUT_F32, int BN>
__global__ __launch_bounds__(256) void gemm_bt_k(
    const unsigned short* __restrict__ A, const unsigned short* __restrict__ Bt,
    const float* __restrict__ bias, void* __restrict__ Cp, int N, int K)
{
  gemm_bt_body<OUT_F32, BN>(A, Bt, bias, Cp, N, K,
                            blockIdx.y * 128, blockIdx.x * BN);
}

// K and V projections fused via blockIdx.z (each alone is only 128-256 blocks).
__global__ __launch_bounds__(256) void gemm_kv_k(
    const unsigned short* __restrict__ Ak, const unsigned short* __restrict__ Av,
    const unsigned short* __restrict__ Btk, const unsigned short* __restrict__ Btv,
    const float* __restrict__ bk, const float* __restrict__ bv,
    unsigned short* __restrict__ Ck, unsigned short* __restrict__ Cv,
    int N, int K)
{
  const bool z = (blockIdx.z != 0);
  gemm_bt_body<0, 64>(z ? Av : Ak, z ? Btv : Btk, z ? bv : bk,
                      z ? (void*)Cv : (void*)Ck, N, K,
                      blockIdx.y * 128, blockIdx.x * 64);
}

// In-place NeoX RoPE on bf16 X [B,T,nheads,HD]. One thread per (b,t,h,pair).
__global__ __launch_bounds__(256) void rope_k(unsigned short* __restrict__ X,
                                              int nheads, int total)
{
  int idx = blockIdx.x * 256 + threadIdx.x;
  if (idx >= total) return;
  int i = idx & 63;
  int rem = idx >> 6;                 // (b*T + t)*nheads + h
  int t = (rem / nheads) % T_;
  size_t base = (size_t)rem * HD_;
  float inv = expf(-9.210340371976184f * (float)(2 * i) * (1.0f / 128.0f));
  float ph = (float)t * inv;
  float sp, cp;
  sincosf(ph, &sp, &cp);
  float x1 = b2f(X[base + i]);
  float x2 = b2f(X[base + 64 + i]);
  X[base + i]      = f2b(x1 * cp - x2 * sp);
  X[base + 64 + i] = f2b(x2 * cp + x1 * sp);
}

// Flash attention: 4 independent waves/block, each owns 16 q-rows of one
// (b,h). Key tiles of 32, online softmax, tanh softcap, causal. bf16 in/out.
__global__ __launch_bounds__(256) void attn_k(
    const unsigned short* __restrict__ Q,   // [B,T,NQ,HD]
    const unsigned short* __restrict__ Kb,  // [B,T,NKV,HD]
    const unsigned short* __restrict__ Vb,  // [B,T,NKV,HD]
    unsigned short* __restrict__ O)         // [B,T,NQ,HD]
{
  __shared__ unsigned short Pls[4][16][32];
  const int tid = threadIdx.x;
  const int wave = tid >> 6;
  const int lane = tid & 63;
  const int quad = lane >> 4;
  const int l16 = lane & 15;
  const int b = blockIdx.z;
  const int h = blockIdx.y;
  const int hk = h / GQ_;
  const int t0 = blockIdx.x * 64 + wave * 16;

  bf8_t qf[4];
  {
    const unsigned short* qp =
        Q + ((size_t)(b * T_ + t0 + l16) * NQ_ + h) * HD_ + quad * 8;
    #pragma unroll
    for (int i = 0; i < 4; i++) qf[i] = ld_frag(qp + i * 32);
  }

  f4 accO[8];
  #pragma unroll
  for (int i = 0; i < 8; i++) accO[i] = f4{0.f, 0.f, 0.f, 0.f};
  float mrow[4] = {-1e30f, -1e30f, -1e30f, -1e30f};
  float lrow[4] = {0.f, 0.f, 0.f, 0.f};

  const int kend = t0 + 16;
  for (int t1 = 0; t1 < kend; t1 += 32) {
    f4 s0 = f4{0.f,0.f,0.f,0.f}, s1 = f4{0.f,0.f,0.f,0.f};
    {
      const unsigned short* kp0 =
          Kb + ((size_t)(b * T_ + t1 + l16) * NKV_ + hk) * HD_ + quad * 8;
      const unsigned short* kp1 = kp0 + 16 * NKV_ * HD_;
      #pragma unroll
      for (int i = 0; i < 4; i++) {
        s0 = mfma16x16(qf[i], ld_frag(kp0 + i * 32), s0);
        s1 = mfma16x16(qf[i], ld_frag(kp1 + i * 32), s1);
      }
    }
    #pragma unroll
    for (int r = 0; r < 4; r++) {
      int qg = t0 + quad * 4 + r;
      float v0 = s0[r] * MULT_;
      float v1 = s1[r] * MULT_;
      v0 = MAXATTN_ * tanhf(v0 * (1.0f / MAXATTN_));
      v1 = MAXATTN_ * tanhf(v1 * (1.0f / MAXATTN_));
      if (t1 + l16 > qg)      v0 = -1e30f;
      if (t1 + 16 + l16 > qg) v1 = -1e30f;
      float tmax = fmaxf(v0, v1);
      #pragma unroll
      for (int off = 1; off < 16; off <<= 1)
        tmax = fmaxf(tmax, __shfl_xor(tmax, off, 16));
      float mnew = fmaxf(mrow[r], tmax);
      float alpha = __expf(mrow[r] - mnew);
      float p0 = __expf(v0 - mnew);
      float p1 = __expf(v1 - mnew);
      float ps = p0 + p1;
      #pragma unroll
      for (int off = 1; off < 16; off <<= 1)
        ps += __shfl_xor(ps, off, 16);
      lrow[r] = lrow[r] * alpha + ps;
      mrow[r] = mnew;
      #pragma unroll
      for (int nt = 0; nt < 8; nt++) accO[nt][r] *= alpha;
      Pls[wave][quad * 4 + r][l16]      = f2b(p0);
      Pls[wave][quad * 4 + r][16 + l16] = f2b(p1);
    }
    __threadfence_block();
    bf8_t pfrag = ld_frag(&Pls[wave][l16][quad * 8]);
    const unsigned short* vp =
        Vb + ((size_t)(b * T_ + t1) * NKV_ + hk) * HD_ + l16;
    #pragma unroll
    for (int nt = 0; nt < 8; nt++) {
      short8 vv;
      #pragma unroll
      for (int j = 0; j < 8; j++)
        vv[j] = (short)vp[(size_t)(quad * 8 + j) * (NKV_ * HD_) + nt * 16];
      accO[nt] = mfma16x16(pfrag, __builtin_bit_cast(bf8_t, vv), accO[nt]);
    }
  }

  float invl[4];
  #pragma unroll
  for (int r = 0; r < 4; r++) invl[r] = 1.0f / lrow[r];
  #pragma unroll
  for (int nt = 0; nt < 8; nt++) {
    #pragma unroll
    for (int r = 0; r < 4; r++) {
      int tg = t0 + quad * 4 + r;
      O[((size_t)(b * T_ + tg) * NQ_ + h) * HD_ + nt * 16 + l16] =
          f2b(accO[nt][r] * invl[r]);
    }
  }
}

extern "C" void kernel_launch(void* const* d_in, const int* in_sizes, int n_in,
                              void* d_out, int out_size, void* d_ws, size_t ws_size,
                              hipStream_t stream)
{
  const float* q_in = (const float*)d_in[0];
  const float* k_in = (const float*)d_in[1];
  const float* v_in = (const float*)d_in[2];
  // d_in[3] = mask (causal tril) — hard-coded in attn_k
  const float* wq = (const float*)d_in[4];
  const float* bq = (const float*)d_in[5];
  const float* wk = (const float*)d_in[6];
  const float* bk = (const float*)d_in[7];
  const float* wv = (const float*)d_in[8];
  const float* bv = (const float*)d_in[9];
  const float* wo = (const float*)d_in[10];

  // Workspace layout (128 MiB total). Sequential stream order makes the
  // overlays safe:
  //   WT  [0,   75.5M)  : wq^T bf16, then (after Q-gemm) wo^T bf16
  //   WKt [75.5M, 88.1M): wk^T bf16   \ overlaid later by
  //   WVt [88.1M,100.7M): wv^T bf16   / Ab (attn out, 25.2M) after KV-gemm
  //   Qb  [100.7M,125.8M), Kb [125.8M,130.0M), Vb [130.0M,134.2M)
  // Activations bf16 live in d_out (50.3 MB, unused until final O-gemm):
  //   Xq = d_out[0,25.2M); then Xk = same region, Xv = d_out[25.2M,50.3M)
  char* ws = (char*)d_ws;
  unsigned short* WT  = (unsigned short*)(ws);
  unsigned short* WKt = (unsigned short*)(ws + 75497472);
  unsigned short* WVt = (unsigned short*)(ws + 88080384);
  unsigned short* Ab  = (unsigned short*)(ws + 75497472);
  unsigned short* Qb  = (unsigned short*)(ws + 100663296);
  unsigned short* Kb  = (unsigned short*)(ws + 125829120);
  unsigned short* Vb  = (unsigned short*)(ws + 130023424);
  unsigned short* Xq  = (unsigned short*)d_out;
  unsigned short* Xk  = (unsigned short*)d_out;
  unsigned short* Xv  = (unsigned short*)d_out + 12582912;

  dim3 blk(256);
  dim3 tb(32, 8);

  // activations + weight transposes for Q stage
  conv_bf16_k<<<6144, blk, 0, stream>>>(q_in, Xq);
  transpose_w_k<<<dim3(192, 96), tb, 0, stream>>>(wq, WT, D_, NQ_ * HD_);
  transpose_w_k<<<dim3(32, 96), tb, 0, stream>>>(wk, WKt, D_, NKV_ * HD_);
  transpose_w_k<<<dim3(32, 96), tb, 0, stream>>>(wv, WVt, D_, NKV_ * HD_);

  // Q projection: [2048,6144] = Xq @ wq^T
  gemm_bt_k<0, 128><<<dim3(48, 16), blk, 0, stream>>>(
      Xq, WT, bq, Qb, NQ_ * HD_, D_);

  // reuse d_out scratch for k/v activations; wo^T into WT (wq^T dead now)
  conv_bf16_k<<<6144, blk, 0, stream>>>(k_in, Xk);
  conv_bf16_k<<<6144, blk, 0, stream>>>(v_in, Xv);
  transpose_w_k<<<dim3(192, 96), tb, 0, stream>>>(wo, WT, NQ_ * HD_, D_);

  // K and V projections fused (z=2), 128x64 tiles -> 512 blocks
  gemm_kv_k<<<dim3(16, 16, 2), blk, 0, stream>>>(
      Xk, Xv, WKt, WVt, bk, bv, Kb, Vb, NKV_ * HD_, D_);

  rope_k<<<(B_ * T_ * NQ_ * 64) / 256, blk, 0, stream>>>(
      Qb, NQ_, B_ * T_ * NQ_ * 64);
  rope_k<<<(B_ * T_ * NKV_ * 64) / 256, blk, 0, stream>>>(
      Kb, NKV_, B_ * T_ * NKV_ * 64);

  attn_k<<<dim3(T_ / 64, NQ_, B_), blk, 0, stream>>>(Qb, Kb, Vb, Ab);

  // Output projection: out[2048,6144] = Ab @ wo^T (fp32 out, no bias)
  gemm_bt_k<1, 128><<<dim3(48, 16), blk, 0, stream>>>(
      Ab, WT, nullptr, d_out, D_, NQ_ * HD_);
}

// Round 2
// 1255.558 us; speedup vs baseline: 2.0338x; 1.0758x over previous
//
#include <hip/hip_runtime.h>
#include <hip/hip_bf16.h>

#define B_ 2
#define T_ 1024
#define D_ 6144
#define NQ_ 48
#define NKV_ 8
#define HD_ 128
#define GQ_ 6
#define MULT_ 0.08838834764831845f
#define MAXATTN_ 30.0f

typedef __bf16 bf8_t __attribute__((ext_vector_type(8)));
typedef short short8 __attribute__((ext_vector_type(8)));
typedef short short4v __attribute__((ext_vector_type(4)));
typedef float f4 __attribute__((ext_vector_type(4)));

__device__ inline float b2f(unsigned short u) {
  return __uint_as_float(((unsigned int)u) << 16);
}
__device__ inline unsigned short f2b(float f) {
  unsigned int u = __float_as_uint(f);
  u += 0x7FFFu + ((u >> 16) & 1u);
  return (unsigned short)(u >> 16);
}
__device__ inline bf8_t ld_frag(const unsigned short* p) {
  return __builtin_bit_cast(bf8_t, *reinterpret_cast<const short8*>(p));
}
__device__ inline f4 mfma16x16(bf8_t a, bf8_t b, f4 c) {
  return __builtin_amdgcn_mfma_f32_16x16x32_bf16(a, b, c, 0, 0, 0);
}
// Async global->LDS, 16B per lane. LDS dest is wave-uniform base; HW writes
// base + lane*16 (m104/m108). Global src per-lane.
__device__ __forceinline__ void gld_lds16(const void* g, void* l) {
  __builtin_amdgcn_global_load_lds(
      (__attribute__((address_space(1))) void*)g,
      (__attribute__((address_space(3))) void*)l, 16, 0, 0);
}

// fp32 -> bf16 flat convert, 8 elems/thread, exact-multiple grids only.
__global__ __launch_bounds__(256) void conv_bf16_k(
    const float* __restrict__ x, unsigned short* __restrict__ y)
{
  size_t i = (size_t)blockIdx.x * 256 + threadIdx.x;
  const f4* xv = (const f4*)x;
  f4 a = xv[2 * i], b = xv[2 * i + 1];
  short8 o;
  #pragma unroll
  for (int j = 0; j < 4; ++j) {
    o[j] = (short)f2b(a[j]);
    o[4 + j] = (short)f2b(b[j]);
  }
  *((short8*)y + i) = o;
}

// W fp32 [K][N] -> Wt bf16 [N][K]. blockDim (32,8); tile: 64 k x 32 n.
__global__ __launch_bounds__(256) void transpose_w_k(
    const float* __restrict__ W, unsigned short* __restrict__ Wt, int K, int N)
{
  __shared__ float t[64][33];
  const int nb = blockIdx.x * 32;
  const int kb = blockIdx.y * 64;
  const int tx = threadIdx.x;  // 0..31
  const int ty = threadIdx.y;  // 0..7
  #pragma unroll
  for (int j = ty; j < 64; j += 8)
    t[j][tx] = W[(size_t)(kb + j) * N + nb + tx];  // coalesced 128B rows
  __syncthreads();
  #pragma unroll
  for (int j = ty; j < 32; j += 8) {
    unsigned int pk = (unsigned int)f2b(t[2 * tx][j]) |
                      ((unsigned int)f2b(t[2 * tx + 1][j]) << 16);
    // packed 4B stores: 32 lanes -> 128B coalesced lines along k
    *reinterpret_cast<unsigned int*>(&Wt[(size_t)(nb + j) * K + kb + 2 * tx]) = pk;
  }
}

// ---------------------------------------------------------------------------
// m97-structure GEMM: C[M,N] = A[M,K] @ Bt[N,K]^T + bias.
// A, Bt bf16 k-contiguous. 128 x BN tile, 4 waves (2x2), K-step 32.
// Both operands staged via global_load_lds width=16 (linear LDS layout).
// OUT: 0 = bf16 row-major, 1 = fp32 row-major,
//      2 = bf16 transposed-for-attn-V: C[(b*1024+gn)*1024 + (gm&1023)]
//          (requires N==1024, M==B_*T_, bias non-null)
// ---------------------------------------------------------------------------
template <int OUT, int BN>
__device__ __forceinline__ void gemm_bt_body(
    const unsigned short* __restrict__ A, const unsigned short* __restrict__ Bt,
    const float* __restrict__ bias, void* __restrict__ Cp,
    int N, int K, int m0, int n0)
{
  constexpr int WN = BN / 2;   // cols per wave
  constexpr int FB = BN / 32;  // b-frags per wave
  constexpr int RB = BN / 64;  // B staging rounds
  __shared__ unsigned short As[128 * 32];
  __shared__ unsigned short Bs[BN * 32];
  const int tid = threadIdx.x;
  const int wave = tid >> 6;
  const int lane = tid & 63;
  const int quad = lane >> 4;
  const int l16 = lane & 15;
  const int wr = wave >> 1;  // wave row 0..1 (64 rows each)
  const int wc = wave & 1;   // wave col 0..1 (WN cols each)
  const int srow = tid >> 2;
  const int skc = (tid & 3) * 8;

  f4 acc[4][FB];
  #pragma unroll
  for (int i = 0; i < 4; ++i)
    #pragma unroll
    for (int j = 0; j < FB; ++j) acc[i][j] = f4{0.f, 0.f, 0.f, 0.f};

  for (int k0 = 0; k0 < K; k0 += 32) {
    #pragma unroll
    for (int r = 0; r < 2; ++r)
      gld_lds16(A + (size_t)(m0 + r * 64 + srow) * K + k0 + skc,
                &As[(r * 256 + wave * 64) * 8]);
    #pragma unroll
    for (int r = 0; r < RB; ++r)
      gld_lds16(Bt + (size_t)(n0 + r * 64 + srow) * K + k0 + skc,
                &Bs[(r * 256 + wave * 64) * 8]);
    __syncthreads();  // compiler emits vmcnt(0) drain before s_barrier
    bf8_t af[4], bfr[FB];
    #pragma unroll
    for (int i = 0; i < 4; ++i)
      af[i] = ld_frag(&As[(wr * 64 + i * 16 + l16) * 32 + quad * 8]);
    #pragma unroll
    for (int j = 0; j < FB; ++j)
      bfr[j] = ld_frag(&Bs[(wc * WN + j * 16 + l16) * 32 + quad * 8]);
    #pragma unroll
    for (int i = 0; i < 4; ++i)
      #pragma unroll
      for (int j = 0; j < FB; ++j)
        acc[i][j] = mfma16x16(af[i], bfr[j], acc[i][j]);
    __syncthreads();
  }

  #pragma unroll
  for (int j = 0; j < FB; ++j) {
    const int gn = n0 + wc * WN + j * 16 + l16;
    const float bv = (OUT == 1) ? (bias ? bias[gn] : 0.f) : bias[gn];
    #pragma unroll
    for (int i = 0; i < 4; ++i) {
      if constexpr (OUT == 2) {
        const int gm0 = m0 + wr * 64 + i * 16 + quad * 4;
        const int bb = gm0 >> 10;
        const int tt = gm0 & 1023;
        short4v pk;
        #pragma unroll
        for (int r = 0; r < 4; ++r) pk[r] = (short)f2b(acc[i][j][r] + bv);
        *reinterpret_cast<short4v*>(
            &((unsigned short*)Cp)[((size_t)(bb * 1024 + gn)) * 1024 + tt]) = pk;
      } else {
        #pragma unroll
        for (int r = 0; r < 4; ++r) {
          const int gm = m0 + wr * 64 + i * 16 + quad * 4 + r;
          const float v = acc[i][j][r] + bv;
          if constexpr (OUT == 1)
            ((float*)Cp)[(size_t)gm * N + gn] = v;
          else
            ((unsigned short*)Cp)[(size_t)gm * N + gn] = f2b(v);
        }
      }
    }
  }
}

template <int OUT, int BN>
__global__ __launch_bounds__(256) void gemm_bt_k(
    const unsigned short* __restrict__ A, const unsigned short* __restrict__ Bt,
    const float* __restrict__ bias, void* __restrict__ Cp, int N, int K)
{
  gemm_bt_body<OUT, BN>(A, Bt, bias, Cp, N, K,
                        blockIdx.y * 128, blockIdx.x * BN);
}

// K and V projections fused via blockIdx.z. K -> row-major bf16 (for RoPE);
// V -> transposed [B][NKV*HD][T] for the attention PV B-operand.
__global__ __launch_bounds__(256) void gemm_kv_k(
    const unsigned short* __restrict__ Ak, const unsigned short* __restrict__ Av,
    const unsigned short* __restrict__ Btk, const unsigned short* __restrict__ Btv,
    const float* __restrict__ bk, const float* __restrict__ bv,
    unsigned short* __restrict__ Ck, unsigned short* __restrict__ Cvt,
    int N, int K)
{
  if (blockIdx.z == 0)
    gemm_bt_body<0, 64>(Ak, Btk, bk, Ck, N, K, blockIdx.y * 128, blockIdx.x * 64);
  else
    gemm_bt_body<2, 64>(Av, Btv, bv, Cvt, N, K, blockIdx.y * 128, blockIdx.x * 64);
}

// In-place NeoX RoPE on bf16 X [B,T,nheads,HD]. One thread per (b,t,h,pair).
__global__ __launch_bounds__(256) void rope_k(unsigned short* __restrict__ X,
                                              int nheads, int total)
{
  int idx = blockIdx.x * 256 + threadIdx.x;
  if (idx >= total) return;
  int i = idx & 63;
  int rem = idx >> 6;                 // (b*T + t)*nheads + h
  int t = (rem / nheads) % T_;
  size_t base = (size_t)rem * HD_;
  float inv = expf(-9.210340371976184f * (float)(2 * i) * (1.0f / 128.0f));
  float ph = (float)t * inv;
  float sp, cp;
  sincosf(ph, &sp, &cp);
  float x1 = b2f(X[base + i]);
  float x2 = b2f(X[base + 64 + i]);
  X[base + i]      = f2b(x1 * cp - x2 * sp);
  X[base + 64 + i] = f2b(x2 * cp + x1 * sp);
}

// ---------------------------------------------------------------------------
// Flash attention, static-max softmax.
// logits are tanh-capped at +-MAXATTN, so row-max <= 30 statically:
//   p = exp(30*tanh(s*MULT/30) - 30) = exp(-60 / (exp(s*2*MULT/30) + 1))
// -> no running max, no per-tile reductions, no accumulator rescale.
// l is accumulated per-lane and reduced once at the end.
// Each wave owns 16 q-rows; block processes q-tile pair (x, 15-x) for
// causal load balance. V is pre-transposed: Vt[b][hk][d][t].
// ---------------------------------------------------------------------------
__device__ __forceinline__ void attn_qtile(
    const unsigned short* __restrict__ Q, const unsigned short* __restrict__ Kb,
    const unsigned short* __restrict__ Vt, unsigned short* __restrict__ O,
    unsigned short* __restrict__ Pw,  // this wave's [16][32] P tile in LDS
    int b, int h, int hk, int t0, int quad, int l16)
{
  bf8_t qf[4];
  {
    const unsigned short* qp =
        Q + ((size_t)(b * T_ + t0 + l16) * NQ_ + h) * HD_ + quad * 8;
    #pragma unroll
    for (int i = 0; i < 4; i++) qf[i] = ld_frag(qp + i * 32);
  }

  f4 accO[8];
  #pragma unroll
  for (int i = 0; i < 8; i++) accO[i] = f4{0.f, 0.f, 0.f, 0.f};
  float lpart[4] = {0.f, 0.f, 0.f, 0.f};

  const unsigned short* vbase = Vt + (size_t)(b * NKV_ + hk) * HD_ * T_;
  const int kend = t0 + 16;
  for (int t1 = 0; t1 < kend; t1 += 32) {
    f4 s0 = f4{0.f,0.f,0.f,0.f}, s1 = f4{0.f,0.f,0.f,0.f};
    {
      const unsigned short* kp0 =
          Kb + ((size_t)(b * T_ + t1 + l16) * NKV_ + hk) * HD_ + quad * 8;
      const unsigned short* kp1 = kp0 + 16 * NKV_ * HD_;
      #pragma unroll
      for (int i = 0; i < 4; i++) {
        s0 = mfma16x16(qf[i], ld_frag(kp0 + i * 32), s0);
        s1 = mfma16x16(qf[i], ld_frag(kp1 + i * 32), s1);
      }
    }
    #pragma unroll
    for (int r = 0; r < 4; r++) {
      const int qg = t0 + quad * 4 + r;
      float e0 = __expf(s0[r] * (2.f * MULT_ / MAXATTN_));
      float e1 = __expf(s1[r] * (2.f * MULT_ / MAXATTN_));
      float p0 = __expf(-2.f * MAXATTN_ * __builtin_amdgcn_rcpf(e0 + 1.f));
      float p1 = __expf(-2.f * MAXATTN_ * __builtin_amdgcn_rcpf(e1 + 1.f));
      if (t1 + l16 > qg)      p0 = 0.f;
      if (t1 + 16 + l16 > qg) p1 = 0.f;
      lpart[r] += p0 + p1;
      Pw[(quad * 4 + r) * 32 + l16]      = f2b(p0);
      Pw[(quad * 4 + r) * 32 + 16 + l16] = f2b(p1);
    }
    __threadfence_block();
    bf8_t pfrag = ld_frag(&Pw[l16 * 32 + quad * 8]);
    #pragma unroll
    for (int nt = 0; nt < 8; nt++) {
      bf8_t vf = ld_frag(vbase + (size_t)(nt * 16 + l16) * T_ + t1 + quad * 8);
      accO[nt] = mfma16x16(pfrag, vf, accO[nt]);
    }
  }

  float invl[4];
  #pragma unroll
  for (int r = 0; r < 4; r++) {
    float s = lpart[r];
    #pragma unroll
    for (int off = 1; off < 16; off <<= 1) s += __shfl_xor(s, off, 16);
    invl[r] = __builtin_amdgcn_rcpf(s);
  }
  #pragma unroll
  for (int nt = 0; nt < 8; nt++) {
    #pragma unroll
    for (int r = 0; r < 4; r++) {
      const int tg = t0 + quad * 4 + r;
      O[((size_t)(b * T_ + tg) * NQ_ + h) * HD_ + nt * 16 + l16] =
          f2b(accO[nt][r] * invl[r]);
    }
  }
}

__global__ __launch_bounds__(256) void attn_k(
    const unsigned short* __restrict__ Q,   // [B,T,NQ,HD]
    const unsigned short* __restrict__ Kb,  // [B,T,NKV,HD]
    const unsigned short* __restrict__ Vt,  // [B,NKV,HD,T]
    unsigned short* __restrict__ O)         // [B,T,NQ,HD]
{
  __shared__ unsigned short Pls[4][16][32];
  const int tid = threadIdx.x;
  const int wave = tid >> 6;
  const int lane = tid & 63;
  const int quad = lane >> 4;
  const int l16 = lane & 15;
  const int b = blockIdx.z;
  const int h = blockIdx.y;
  const int hk = h / GQ_;
  unsigned short* Pw = &Pls[wave][0][0];

  const int xa = blockIdx.x;                 // 0..7
  const int xh = (T_ / 64 - 1) - xa;         // heavy partner: 15-xa
  attn_qtile(Q, Kb, Vt, O, Pw, b, h, hk, xh * 64 + wave * 16, quad, l16);
  attn_qtile(Q, Kb, Vt, O, Pw, b, h, hk, xa * 64 + wave * 16, quad, l16);
}

extern "C" void kernel_launch(void* const* d_in, const int* in_sizes, int n_in,
                              void* d_out, int out_size, void* d_ws, size_t ws_size,
                              hipStream_t stream)
{
  const float* q_in = (const float*)d_in[0];
  const float* k_in = (const float*)d_in[1];
  const float* v_in = (const float*)d_in[2];
  // d_in[3] = mask (causal tril) — hard-coded in attn_k
  const float* wq = (const float*)d_in[4];
  const float* bq = (const float*)d_in[5];
  const float* wk = (const float*)d_in[6];
  const float* bk = (const float*)d_in[7];
  const float* wv = (const float*)d_in[8];
  const float* bv = (const float*)d_in[9];
  const float* wo = (const float*)d_in[10];

  // Workspace layout (128 MiB). Sequential stream order makes overlays safe:
  //   WT  [0,   75.5M)  : wq^T bf16, then (after Q-gemm) wo^T bf16
  //   WKt [75.5M, 88.1M): wk^T bf16   \ overlaid later by
  //   WVt [88.1M,100.7M): wv^T bf16   / Ab (attn out, 25.2M) after KV-gemm
  //   Qb  [100.7M,125.8M), Kb [125.8M,130.0M), Vt [130.0M,134.2M)
  // Activations bf16 live in d_out (50.3 MB, unused until final O-gemm).
  char* ws = (char*)d_ws;
  unsigned short* WT  = (unsigned short*)(ws);
  unsigned short* WKt = (unsigned short*)(ws + 75497472);
  unsigned short* WVt = (unsigned short*)(ws + 88080384);
  unsigned short* Ab  = (unsigned short*)(ws + 75497472);
  unsigned short* Qb  = (unsigned short*)(ws + 100663296);
  unsigned short* Kb  = (unsigned short*)(ws + 125829120);
  unsigned short* Vt  = (unsigned short*)(ws + 130023424);
  unsigned short* Xq  = (unsigned short*)d_out;
  unsigned short* Xk  = (unsigned short*)d_out;
  unsigned short* Xv  = (unsigned short*)d_out + 12582912;

  dim3 blk(256);
  dim3 tb(32, 8);

  // activations + weight transposes for Q stage
  conv_bf16_k<<<6144, blk, 0, stream>>>(q_in, Xq);
  transpose_w_k<<<dim3(192, 96), tb, 0, stream>>>(wq, WT, D_, NQ_ * HD_);
  transpose_w_k<<<dim3(32, 96), tb, 0, stream>>>(wk, WKt, D_, NKV_ * HD_);
  transpose_w_k<<<dim3(32, 96), tb, 0, stream>>>(wv, WVt, D_, NKV_ * HD_);

  // Q projection: [2048,6144] = Xq @ wq^T
  gemm_bt_k<0, 128><<<dim3(48, 16), blk, 0, stream>>>(
      Xq, WT, bq, Qb, NQ_ * HD_, D_);

  // reuse d_out scratch for k/v activations; wo^T into WT (wq^T dead now)
  conv_bf16_k<<<6144, blk, 0, stream>>>(k_in, Xk);
  conv_bf16_k<<<6144, blk, 0, stream>>>(v_in, Xv);
  transpose_w_k<<<dim3(192, 96), tb, 0, stream>>>(wo, WT, NQ_ * HD_, D_);

  // K and V projections fused (z=2); V written transposed for attention
  gemm_kv_k<<<dim3(16, 16, 2), blk, 0, stream>>>(
      Xk, Xv, WKt, WVt, bk, bv, Kb, Vt, NKV_ * HD_, D_);

  rope_k<<<(B_ * T_ * NQ_ * 64) / 256, blk, 0, stream>>>(
      Qb, NQ_, B_ * T_ * NQ_ * 64);
  rope_k<<<(B_ * T_ * NKV_ * 64) / 256, blk, 0, stream>>>(
      Kb, NKV_, B_ * T_ * NKV_ * 64);

  // balanced causal pairing: grid.x = 8 (tile pairs x, 15-x)
  attn_k<<<dim3(T_ / 128, NQ_, B_), blk, 0, stream>>>(Qb, Kb, Vt, Ab);

  // Output projection: out[2048,6144] = Ab @ wo^T (fp32 out, no bias)
  gemm_bt_k<1, 128><<<dim3(48, 16), blk, 0, stream>>>(
      Ab, WT, nullptr, d_out, D_, NQ_ * HD_);
}